// Round 1
// baseline (96.555 us; speedup 1.0000x reference)
//
#include <hip/hip_runtime.h>
#include <cstdint>
#include <cstddef>

#define BATCH  8
#define SEQ    4096
#define CHN    256        // channels (OUT)
#define NQ     768        // 3*OUT
#define KTOT   512        // WIN*IN
#define TS     64         // seq rows per GEMM tile / scan chunk
#define NCHUNK (SEQ/TS)   // 64

typedef __attribute__((ext_vector_type(8))) __bf16    bf16x8;
typedef __attribute__((ext_vector_type(4))) __bf16    bf16x4;
typedef __attribute__((ext_vector_type(4))) float     f32x4;
typedef __attribute__((ext_vector_type(4))) _Float16  f16x4;

// ---------------------------------------------------------------------------
// K0: convert W (fp32 [768][512]) into frag-major bf16 tiles:
//     Wt[(t*4+g)*768 + n][j] = bf16(W[n][t*32 + g*8 + j]),  t<16, g<4, j<8
// so a wave's A-fragment load (lanes 0-15 = consecutive n) is 256B-contiguous.
// ---------------------------------------------------------------------------
__global__ __launch_bounds__(256) void k_convW(const float* __restrict__ W,
                                               __bf16* __restrict__ Wt) {
    int lin = blockIdx.x * 256 + threadIdx.x;   // 0 .. 49151  (= 64*768)
    int n  = lin % NQ;
    int tg = lin / NQ;                          // t*4+g, 0..63
    const float* src = W + (size_t)n * KTOT + tg * 8;
    float4 a = *(const float4*)(src);
    float4 b = *(const float4*)(src + 4);
    bf16x8 h;
    h[0]=(__bf16)a.x; h[1]=(__bf16)a.y; h[2]=(__bf16)a.z; h[3]=(__bf16)a.w;
    h[4]=(__bf16)b.x; h[5]=(__bf16)b.y; h[6]=(__bf16)b.z; h[7]=(__bf16)b.w;
    *(bf16x8*)(Wt + (size_t)lin * 8) = h;
}

// ---------------------------------------------------------------------------
// K1: GEMM (transposed: y^T = W * xw^T) + activations.
// Grid: 8 batches * 64 chunks; block 512 = 8 waves; wave w owns n in [96w,96w+96).
// Writes Z = tanh(y_z), F = sigmoid(y_f), O = sigmoid(y_o) as fp16 [b][s][ch].
// ---------------------------------------------------------------------------
__global__ __launch_bounds__(512, 2) void k_gemm(
    const float* __restrict__ x, const __bf16* __restrict__ Wt,
    const float* __restrict__ bias,
    _Float16* __restrict__ Zb, _Float16* __restrict__ Fb, _Float16* __restrict__ Ob)
{
    __shared__ __bf16 As[65 * 256];   // rows s0-1 .. s0+63, XOR-swizzled

    int tid = threadIdx.x;
    int bi  = blockIdx.x >> 6;
    int ck  = blockIdx.x & 63;
    int s0  = ck * TS;
    int wid = tid >> 6;
    int l   = tid & 63;
    int l15 = l & 15, lg = l >> 4;

    // ---- stage x window (fp32 -> bf16), swizzle byte ^= (row&7)<<4 ----
    for (int i = 0; i < 9; ++i) {
        int idx = tid + i * 512;
        if (idx < 65 * 64) {
            int r  = idx >> 6, cg = idx & 63;
            int srow = s0 - 1 + r;
            float4 v = make_float4(0.f, 0.f, 0.f, 0.f);
            if (srow >= 0)
                v = *(const float4*)(x + ((size_t)bi * SEQ + srow) * CHN + cg * 4);
            bf16x4 h;
            h[0]=(__bf16)v.x; h[1]=(__bf16)v.y; h[2]=(__bf16)v.z; h[3]=(__bf16)v.w;
            int boff = (r * 512 + cg * 8) ^ ((r & 7) << 4);
            *(bf16x4*)((char*)As + boff) = h;
        }
    }
    __syncthreads();

    f32x4 acc[6][4];
    const f32x4 vzero = {0.f, 0.f, 0.f, 0.f};
    #pragma unroll
    for (int a = 0; a < 6; ++a)
        #pragma unroll
        for (int b = 0; b < 4; ++b)
            acc[a][b] = vzero;

    // ---- K loop: 16 steps of K=32; no barriers (As is read-only) ----
    #pragma unroll
    for (int t = 0; t < 16; ++t) {
        int kh  = t >> 3;            // 0: uses x[s-1] (row m), 1: x[s] (row m+1)
        int kc0 = (t & 7) * 32;
        bf16x8 xf[4];
        #pragma unroll
        for (int st = 0; st < 4; ++st) {
            int row  = st * 16 + l15 + kh;
            int boff = (row * 512 + (kc0 + lg * 8) * 2) ^ ((row & 7) << 4);
            xf[st] = *(const bf16x8*)((const char*)As + boff);
        }
        #pragma unroll
        for (int nt = 0; nt < 6; ++nt) {
            int n = wid * 96 + nt * 16 + l15;
            bf16x8 wf = *(const bf16x8*)(Wt + ((size_t)((t * 4 + lg) * NQ + n)) * 8);
            #pragma unroll
            for (int st = 0; st < 4; ++st)
                acc[nt][st] = __builtin_amdgcn_mfma_f32_16x16x32_bf16(
                                  wf, xf[st], acc[nt][st], 0, 0, 0);
        }
    }

    // ---- epilogue: lane owns 4 consecutive channels at fixed s -> 8B stores ----
    #pragma unroll
    for (int nt = 0; nt < 6; ++nt) {
        int nbase = wid * 96 + nt * 16 + lg * 4;
        int which = nbase >> 8;        // 0:z 1:f 2:o (uniform per tile)
        int chn   = nbase & 255;
        float4 bv = *(const float4*)(bias + nbase);
        _Float16* buf = (which == 0) ? Zb : (which == 1) ? Fb : Ob;
        #pragma unroll
        for (int st = 0; st < 4; ++st) {
            int s = s0 + st * 16 + l15;
            f16x4 h;
            #pragma unroll
            for (int r = 0; r < 4; ++r) {
                float bvr = (r == 0) ? bv.x : (r == 1) ? bv.y : (r == 2) ? bv.z : bv.w;
                float y = acc[nt][st][r] + bvr;
                float v;
                if (which == 0) v = tanhf(y);
                else            v = 1.f / (1.f + __expf(-y));
                h[r] = (_Float16)v;
            }
            *(f16x4*)(buf + ((size_t)bi * SEQ + s) * CHN + chn) = h;
        }
    }
}

// ---------------------------------------------------------------------------
// K2: per-chunk scan summaries. One block per (batch, chunk); thread = channel.
//     A = prod f over chunk; B = chunk-local scan end value (c0 = 0).
// ---------------------------------------------------------------------------
__global__ __launch_bounds__(256) void k_scan1(const _Float16* __restrict__ Fb,
                                               const _Float16* __restrict__ Zb,
                                               float* __restrict__ Aq,
                                               float* __restrict__ Bq) {
    int bi = blockIdx.x >> 6;
    int ck = blockIdx.x & 63;
    int ch = threadIdx.x;
    size_t base = ((size_t)bi * SEQ + ck * TS) * CHN + ch;
    float a = 1.f, c = 0.f;
    #pragma unroll 8
    for (int s = 0; s < TS; ++s) {
        float f = (float)Fb[base + (size_t)s * CHN];
        float z = (float)Zb[base + (size_t)s * CHN];
        c = f * c + (1.f - f) * z;
        a *= f;
    }
    int o = blockIdx.x * CHN + ch;
    Aq[o] = a;
    Bq[o] = c;
}

// ---------------------------------------------------------------------------
// K3: sequential carry across chunks. 8 blocks (one per batch) x 256 threads.
//     Cq[b][ck][ch] = carry INTO chunk ck.
// ---------------------------------------------------------------------------
__global__ __launch_bounds__(256) void k_scan2(const float* __restrict__ Aq,
                                               const float* __restrict__ Bq,
                                               float* __restrict__ Cq) {
    int bi = blockIdx.x;
    int ch = threadIdx.x;
    float c = 0.f;
    for (int ck = 0; ck < NCHUNK; ++ck) {
        int o = (bi * NCHUNK + ck) * CHN + ch;
        Cq[o] = c;
        c = Aq[o] * c + Bq[o];
    }
}

// ---------------------------------------------------------------------------
// K4: final pass — redo local scan seeded with carry, out = sigmoid(o) * c.
// ---------------------------------------------------------------------------
__global__ __launch_bounds__(256) void k_scan3(const _Float16* __restrict__ Fb,
                                               const _Float16* __restrict__ Zb,
                                               const _Float16* __restrict__ Ob,
                                               const float* __restrict__ Cq,
                                               float* __restrict__ out) {
    int bi = blockIdx.x >> 6;
    int ck = blockIdx.x & 63;
    int ch = threadIdx.x;
    float c = Cq[blockIdx.x * CHN + ch];
    size_t base = ((size_t)bi * SEQ + ck * TS) * CHN + ch;
    #pragma unroll 4
    for (int s = 0; s < TS; ++s) {
        float f  = (float)Fb[base + (size_t)s * CHN];
        float z  = (float)Zb[base + (size_t)s * CHN];
        float so = (float)Ob[base + (size_t)s * CHN];
        c = f * c + (1.f - f) * z;
        out[base + (size_t)s * CHN] = so * c;
    }
}

// ---------------------------------------------------------------------------
extern "C" void kernel_launch(void* const* d_in, const int* in_sizes, int n_in,
                              void* d_out, int out_size, void* d_ws, size_t ws_size,
                              hipStream_t stream)
{
    const float* x = (const float*)d_in[0];   // (8,4096,256) fp32
    const float* W = (const float*)d_in[1];   // (768,512)    fp32
    const float* b = (const float*)d_in[2];   // (768,)       fp32
    float* out = (float*)d_out;               // (8,4096,256) fp32

    char* ws = (char*)d_ws;
    const size_t MB = 1024 * 1024;
    _Float16* Zb = (_Float16*)(ws +  0 * MB);   // 16 MB
    _Float16* Fb = (_Float16*)(ws + 16 * MB);   // 16 MB
    _Float16* Ob = (_Float16*)(ws + 32 * MB);   // 16 MB
    __bf16*   Wt = (__bf16*)  (ws + 48 * MB);   // 768 KB
    float*    Aq = (float*)   (ws + 49 * MB);   // 512 KB
    float*    Bq = (float*)   (ws + 50 * MB);   // 512 KB
    float*    Cq = (float*)   (ws + 51 * MB);   // 512 KB

    k_convW<<<dim3(192),          dim3(256), 0, stream>>>(W, Wt);
    k_gemm <<<dim3(BATCH*NCHUNK), dim3(512), 0, stream>>>(x, Wt, b, Zb, Fb, Ob);
    k_scan1<<<dim3(BATCH*NCHUNK), dim3(256), 0, stream>>>(Fb, Zb, Aq, Bq);
    k_scan2<<<dim3(BATCH),        dim3(256), 0, stream>>>(Aq, Bq, Cq);
    k_scan3<<<dim3(BATCH*NCHUNK), dim3(256), 0, stream>>>(Fb, Zb, Ob, Cq, out);
}

// Round 2
// 87.539 us; speedup vs baseline: 1.1030x; 1.1030x over previous
//
#include <hip/hip_runtime.h>
#include <cstdint>
#include <cstddef>

#define BATCH  8
#define SEQ    4096
#define CHN    256        // channels (OUT)
#define NQ     768        // 3*OUT
#define KTOT   512        // WIN*IN
#define S_B    128        // seq rows per GEMM block
#define TS     128        // scan chunk length
#define NCHUNK (SEQ/TS)   // 32

typedef __attribute__((ext_vector_type(8))) __bf16    bf16x8;
typedef __attribute__((ext_vector_type(4))) __bf16    bf16x4;
typedef __attribute__((ext_vector_type(4))) float     f32x4;
typedef __attribute__((ext_vector_type(4))) _Float16  f16x4;
typedef __attribute__((ext_vector_type(2))) _Float16  f16x2;

// ---------------------------------------------------------------------------
// K0: convert W (fp32 [768][512]) into frag-major bf16 tiles:
//     Wt[(t*4+g)*768 + n][j] = bf16(W[n][t*32 + g*8 + j]),  t<16, g<4, j<8
// ---------------------------------------------------------------------------
__global__ __launch_bounds__(256) void k_convW(const float* __restrict__ W,
                                               __bf16* __restrict__ Wt) {
    int lin = blockIdx.x * 256 + threadIdx.x;   // 0 .. 49151  (= 64*768)
    int n  = lin % NQ;
    int tg = lin / NQ;                          // t*4+g, 0..63
    const float* src = W + (size_t)n * KTOT + tg * 8;
    float4 a = *(const float4*)(src);
    float4 b = *(const float4*)(src + 4);
    bf16x8 h;
    h[0]=(__bf16)a.x; h[1]=(__bf16)a.y; h[2]=(__bf16)a.z; h[3]=(__bf16)a.w;
    h[4]=(__bf16)b.x; h[5]=(__bf16)b.y; h[6]=(__bf16)b.z; h[7]=(__bf16)b.w;
    *(bf16x8*)(Wt + (size_t)lin * 8) = h;
}

__device__ __forceinline__ float fast_sigmoid(float y) {
    float e = __expf(-y);
    return __builtin_amdgcn_rcpf(1.f + e);
}
__device__ __forceinline__ float fast_tanh(float y) {
    float e = __expf(-2.f * y);
    return __builtin_amdgcn_rcpf(1.f + e) * 2.f - 1.f;
}

// ---------------------------------------------------------------------------
// K1: GEMM (transposed: y^T = W * xw^T) + activations.
// Block = 512 thr = 8 waves as (ws in {0,1}) x (wn in {0..3}); wave tile 64n x 64s.
// Block tile: 256 n (one gate, uniform) x 128 s.  Grid = 3 * 8 * 32 = 768.
// acc per wave = 4x4 frags of 16x16 = 64 regs -> unified regcount <= 128.
// ---------------------------------------------------------------------------
__global__ __launch_bounds__(512, 4) void k_gemm(
    const float* __restrict__ x, const __bf16* __restrict__ Wt,
    const float* __restrict__ bias,
    _Float16* __restrict__ Zb, _Float16* __restrict__ Fb, _Float16* __restrict__ Ob)
{
    __shared__ __bf16 As[(S_B + 1) * 256];   // rows s0-1 .. s0+127, XOR-swizzled

    int tid = threadIdx.x;
    int bid = blockIdx.x;
    int nsl  = bid % 3;           // 0:z 1:f 2:o  (fast index -> x-chunk triplets)
    int rest = bid / 3;
    int bi = rest >> 5;
    int sc = rest & 31;
    int s0 = sc * S_B;
    int wid = tid >> 6;
    int l   = tid & 63;
    int l15 = l & 15, lg = l >> 4;
    int wn = wid & 3;             // n-quadrant within 256-gate
    int ws = wid >> 2;            // s-half (0/1), 64 rows each

    // ---- stage x window (fp32 -> bf16), swizzle byte ^= (row&7)<<4 ----
    for (int i = 0; i < 17; ++i) {
        int idx = tid + i * 512;
        if (idx < (S_B + 1) * 64) {
            int r  = idx >> 6, cg = idx & 63;
            int srow = s0 - 1 + r;
            float4 v = make_float4(0.f, 0.f, 0.f, 0.f);
            if (srow >= 0)
                v = *(const float4*)(x + ((size_t)bi * SEQ + srow) * CHN + cg * 4);
            bf16x4 h;
            h[0]=(__bf16)v.x; h[1]=(__bf16)v.y; h[2]=(__bf16)v.z; h[3]=(__bf16)v.w;
            int boff = (r * 512 + cg * 8) ^ ((r & 7) << 4);
            *(bf16x4*)((char*)As + boff) = h;
        }
    }
    __syncthreads();

    f32x4 acc[4][4];
    const f32x4 vzero = {0.f, 0.f, 0.f, 0.f};
    #pragma unroll
    for (int a = 0; a < 4; ++a)
        #pragma unroll
        for (int b = 0; b < 4; ++b)
            acc[a][b] = vzero;

    int nbase = nsl * 256 + wn * 64 + l15;    // + nt*16
    const __bf16* wbase = Wt + ((size_t)lg * NQ + nbase) * 8;

    // ---- K loop: 16 steps of K=32; no barriers (As read-only) ----
    #pragma unroll
    for (int t = 0; t < 16; ++t) {
        int kh  = t >> 3;            // 0: x[s-1], 1: x[s]
        int kc0 = (t & 7) * 32;
        bf16x8 xf[4];
        #pragma unroll
        for (int st = 0; st < 4; ++st) {
            int row  = ws * 64 + st * 16 + l15 + kh;
            int boff = (row * 512 + kc0 * 2 + lg * 16) ^ ((row & 7) << 4);
            xf[st] = *(const bf16x8*)((const char*)As + boff);
        }
        bf16x8 wf[4];
        #pragma unroll
        for (int nt = 0; nt < 4; ++nt)
            wf[nt] = *(const bf16x8*)(wbase + ((size_t)t * 4 * NQ + nt * 16) * 8);
        #pragma unroll
        for (int nt = 0; nt < 4; ++nt)
            #pragma unroll
            for (int st = 0; st < 4; ++st)
                acc[nt][st] = __builtin_amdgcn_mfma_f32_16x16x32_bf16(
                                  wf[nt], xf[st], acc[nt][st], 0, 0, 0);
    }

    // ---- epilogue: gate is block-uniform; lane owns 4 consecutive ch ----
    _Float16* buf = (nsl == 0) ? Zb : (nsl == 1) ? Fb : Ob;
    bool is_tanh = (nsl == 0);
    #pragma unroll
    for (int nt = 0; nt < 4; ++nt) {
        int chb = wn * 64 + nt * 16 + lg * 4;      // channel base (0..255)
        float4 bv = *(const float4*)(bias + nsl * 256 + chb);
        #pragma unroll
        for (int st = 0; st < 4; ++st) {
            int s = s0 + ws * 64 + st * 16 + l15;
            f16x4 h;
            #pragma unroll
            for (int r = 0; r < 4; ++r) {
                float bvr = (r == 0) ? bv.x : (r == 1) ? bv.y : (r == 2) ? bv.z : bv.w;
                float y = acc[nt][st][r] + bvr;
                float v = is_tanh ? fast_tanh(y) : fast_sigmoid(y);
                h[r] = (_Float16)v;
            }
            *(f16x4*)(buf + ((size_t)bi * SEQ + s) * CHN + chb) = h;
        }
    }
}

// ---------------------------------------------------------------------------
// K2: per-chunk scan summaries; thread handles 2 channels (4B f16x2 loads).
//     A = prod f over chunk; B = chunk-local scan end value (c0 = 0).
// ---------------------------------------------------------------------------
__global__ __launch_bounds__(128) void k_scan1(const _Float16* __restrict__ Fb,
                                               const _Float16* __restrict__ Zb,
                                               float* __restrict__ Aq,
                                               float* __restrict__ Bq) {
    int bi = blockIdx.x >> 5;
    int ck = blockIdx.x & 31;
    int c2 = threadIdx.x;                       // channel pair 0..127
    size_t base = (((size_t)bi * SEQ + ck * TS) * CHN + c2 * 2) >> 1; // in f16x2 units
    const f16x2* F2 = (const f16x2*)Fb;
    const f16x2* Z2 = (const f16x2*)Zb;
    float a0 = 1.f, a1 = 1.f, c0 = 0.f, c1 = 0.f;
    #pragma unroll 8
    for (int s = 0; s < TS; ++s) {
        f16x2 f = F2[base + (size_t)s * (CHN / 2)];
        f16x2 z = Z2[base + (size_t)s * (CHN / 2)];
        float f0 = (float)f[0], f1 = (float)f[1];
        c0 = f0 * c0 + (1.f - f0) * (float)z[0];
        c1 = f1 * c1 + (1.f - f1) * (float)z[1];
        a0 *= f0; a1 *= f1;
    }
    int o = blockIdx.x * CHN + c2 * 2;
    *(float2*)(Aq + o) = make_float2(a0, a1);
    *(float2*)(Bq + o) = make_float2(c0, c1);
}

// ---------------------------------------------------------------------------
// K3: sequential carry across chunks. 8 blocks x 256 threads, 32 steps.
// ---------------------------------------------------------------------------
__global__ __launch_bounds__(256) void k_scan2(const float* __restrict__ Aq,
                                               const float* __restrict__ Bq,
                                               float* __restrict__ Cq) {
    int bi = blockIdx.x;
    int ch = threadIdx.x;
    float c = 0.f;
    #pragma unroll
    for (int ck = 0; ck < NCHUNK; ++ck) {
        int o = (bi * NCHUNK + ck) * CHN + ch;
        Cq[o] = c;
        c = Aq[o] * c + Bq[o];
    }
}

// ---------------------------------------------------------------------------
// K4: final pass — redo local scan seeded with carry, out = sigmoid(o) * c.
// ---------------------------------------------------------------------------
__global__ __launch_bounds__(128) void k_scan3(const _Float16* __restrict__ Fb,
                                               const _Float16* __restrict__ Zb,
                                               const _Float16* __restrict__ Ob,
                                               const float* __restrict__ Cq,
                                               float* __restrict__ out) {
    int bi = blockIdx.x >> 5;
    int ck = blockIdx.x & 31;
    int c2 = threadIdx.x;
    float2 c = *(const float2*)(Cq + blockIdx.x * CHN + c2 * 2);
    size_t base = (((size_t)bi * SEQ + ck * TS) * CHN + c2 * 2) >> 1;
    const f16x2* F2 = (const f16x2*)Fb;
    const f16x2* Z2 = (const f16x2*)Zb;
    const f16x2* O2 = (const f16x2*)Ob;
    float* outp = out + (((size_t)bi * SEQ + ck * TS) * CHN + c2 * 2);
    #pragma unroll 4
    for (int s = 0; s < TS; ++s) {
        f16x2 f  = F2[base + (size_t)s * (CHN / 2)];
        f16x2 z  = Z2[base + (size_t)s * (CHN / 2)];
        f16x2 so = O2[base + (size_t)s * (CHN / 2)];
        float f0 = (float)f[0], f1 = (float)f[1];
        c.x = f0 * c.x + (1.f - f0) * (float)z[0];
        c.y = f1 * c.y + (1.f - f1) * (float)z[1];
        *(float2*)(outp + (size_t)s * CHN) = make_float2((float)so[0] * c.x,
                                                         (float)so[1] * c.y);
    }
}

// ---------------------------------------------------------------------------
extern "C" void kernel_launch(void* const* d_in, const int* in_sizes, int n_in,
                              void* d_out, int out_size, void* d_ws, size_t ws_size,
                              hipStream_t stream)
{
    const float* x = (const float*)d_in[0];   // (8,4096,256) fp32
    const float* W = (const float*)d_in[1];   // (768,512)    fp32
    const float* b = (const float*)d_in[2];   // (768,)       fp32
    float* out = (float*)d_out;               // (8,4096,256) fp32

    char* ws = (char*)d_ws;
    const size_t MB = 1024 * 1024;
    _Float16* Zb = (_Float16*)(ws +  0 * MB);   // 16 MB
    _Float16* Fb = (_Float16*)(ws + 16 * MB);   // 16 MB
    _Float16* Ob = (_Float16*)(ws + 32 * MB);   // 16 MB
    __bf16*   Wt = (__bf16*)  (ws + 48 * MB);   // 768 KB
    float*    Aq = (float*)   (ws + 49 * MB);   // 256 KB
    float*    Bq = (float*)   (ws + 50 * MB);   // 256 KB
    float*    Cq = (float*)   (ws + 51 * MB);   // 256 KB

    k_convW<<<dim3(192),            dim3(256), 0, stream>>>(W, Wt);
    k_gemm <<<dim3(3 * BATCH * 32), dim3(512), 0, stream>>>(x, Wt, b, Zb, Fb, Ob);
    k_scan1<<<dim3(BATCH * NCHUNK), dim3(128), 0, stream>>>(Fb, Zb, Aq, Bq);
    k_scan2<<<dim3(BATCH),          dim3(256), 0, stream>>>(Aq, Bq, Cq);
    k_scan3<<<dim3(BATCH * NCHUNK), dim3(128), 0, stream>>>(Fb, Zb, Ob, Cq, out);
}